// Round 1
// baseline (1123.913 us; speedup 1.0000x reference)
//
#include <hip/hip_runtime.h>
#include <cmath>

#define B_ 8
#define N_ 4096
#define D_ 512
#define M_ 512
#define EPS_ 1e-5f
#define DT_ 0.25f

// ---------------------------------------------------------------------------
// Kernel 1: field[b,m,d] = sum_n exp(-(g_m - p_bn)^2 / (2 sigma^2)) * x[b,n,d]
// grid (M/16, B), 256 threads. Thread owns cols (2*tid, 2*tid+1), 16 m-rows.
// kern tile staged in LDS, read as float4 broadcasts (4 n per read -> 8 FMA).
// ---------------------------------------------------------------------------
__global__ __launch_bounds__(256)
void k_project(const float* __restrict__ x, const float* __restrict__ pos,
               const float* __restrict__ gp, const float* __restrict__ log_sigma,
               float* __restrict__ field)
{
    const int tid = threadIdx.x;
    const int b  = blockIdx.y;
    const int m0 = blockIdx.x * 16;

    __shared__ float kern_s[16][256];   // 16 KB
    __shared__ float gs[16];
    if (tid < 16) gs[tid] = gp[b * M_ + m0 + tid];

    const float sigma  = expf(log_sigma[0]);
    const float inv2s2 = 0.5f / (sigma * sigma);

    float acc0[16], acc1[16];
#pragma unroll
    for (int i = 0; i < 16; ++i) { acc0[i] = 0.f; acc1[i] = 0.f; }

    const int c0 = 2 * tid;

    for (int n0 = 0; n0 < N_; n0 += 256) {
        __syncthreads();  // protects kern_s reuse (and gs on first iter)
        const float p = pos[b * N_ + n0 + tid];
#pragma unroll
        for (int mi = 0; mi < 16; ++mi) {
            float dg = gs[mi] - p;
            kern_s[mi][tid] = expf(-dg * dg * inv2s2);
        }
        __syncthreads();

        for (int nn = 0; nn < 256; nn += 4) {
            float2 xv0 = *reinterpret_cast<const float2*>(x + ((size_t)(b * N_ + n0 + nn + 0)) * D_ + c0);
            float2 xv1 = *reinterpret_cast<const float2*>(x + ((size_t)(b * N_ + n0 + nn + 1)) * D_ + c0);
            float2 xv2 = *reinterpret_cast<const float2*>(x + ((size_t)(b * N_ + n0 + nn + 2)) * D_ + c0);
            float2 xv3 = *reinterpret_cast<const float2*>(x + ((size_t)(b * N_ + n0 + nn + 3)) * D_ + c0);
#pragma unroll
            for (int mi = 0; mi < 16; ++mi) {
                float4 k4 = *reinterpret_cast<const float4*>(&kern_s[mi][nn]);
                acc0[mi] = fmaf(k4.x, xv0.x, acc0[mi]);
                acc1[mi] = fmaf(k4.x, xv0.y, acc1[mi]);
                acc0[mi] = fmaf(k4.y, xv1.x, acc0[mi]);
                acc1[mi] = fmaf(k4.y, xv1.y, acc1[mi]);
                acc0[mi] = fmaf(k4.z, xv2.x, acc0[mi]);
                acc1[mi] = fmaf(k4.z, xv2.y, acc1[mi]);
                acc0[mi] = fmaf(k4.w, xv3.x, acc0[mi]);
                acc1[mi] = fmaf(k4.w, xv3.y, acc1[mi]);
            }
        }
    }

#pragma unroll
    for (int mi = 0; mi < 16; ++mi) {
        float2 v; v.x = acc0[mi]; v.y = acc1[mi];
        *reinterpret_cast<float2*>(field + ((size_t)(b * M_ + m0 + mi)) * D_ + c0) = v;
    }
}

// ---------------------------------------------------------------------------
// Kernel 2 (x4, ping-pong): field += dt*(alpha*lap + tanh(field @ W_int + b))
// grid (M/16, B), 256 threads. Stage 16 rows in LDS for the GEMM k-loop.
// ---------------------------------------------------------------------------
__global__ __launch_bounds__(256)
void k_diffuse(const float* __restrict__ fin, const float* __restrict__ Wi,
               const float* __restrict__ bi, const float* __restrict__ alpha_p,
               float* __restrict__ fout)
{
    const int tid = threadIdx.x;
    const int b  = blockIdx.y;
    const int m0 = blockIdx.x * 16;
    const int c0 = 2 * tid;

    __shared__ float fs[16][512];       // 32 KB

#pragma unroll
    for (int mi = 0; mi < 16; ++mi) {
        float2 v = *reinterpret_cast<const float2*>(fin + ((size_t)(b * M_ + m0 + mi)) * D_ + c0);
        *reinterpret_cast<float2*>(&fs[mi][c0]) = v;
    }
    __syncthreads();

    float acc0[16], acc1[16];
#pragma unroll
    for (int i = 0; i < 16; ++i) { acc0[i] = 0.f; acc1[i] = 0.f; }

    for (int k = 0; k < 512; k += 4) {
        float2 w0 = *reinterpret_cast<const float2*>(Wi + (size_t)(k + 0) * D_ + c0);
        float2 w1 = *reinterpret_cast<const float2*>(Wi + (size_t)(k + 1) * D_ + c0);
        float2 w2 = *reinterpret_cast<const float2*>(Wi + (size_t)(k + 2) * D_ + c0);
        float2 w3 = *reinterpret_cast<const float2*>(Wi + (size_t)(k + 3) * D_ + c0);
#pragma unroll
        for (int mi = 0; mi < 16; ++mi) {
            float4 f4 = *reinterpret_cast<const float4*>(&fs[mi][k]);
            acc0[mi] = fmaf(f4.x, w0.x, acc0[mi]);
            acc1[mi] = fmaf(f4.x, w0.y, acc1[mi]);
            acc0[mi] = fmaf(f4.y, w1.x, acc0[mi]);
            acc1[mi] = fmaf(f4.y, w1.y, acc1[mi]);
            acc0[mi] = fmaf(f4.z, w2.x, acc0[mi]);
            acc1[mi] = fmaf(f4.z, w2.y, acc1[mi]);
            acc0[mi] = fmaf(f4.w, w3.x, acc0[mi]);
            acc1[mi] = fmaf(f4.w, w3.y, acc1[mi]);
        }
    }

    const float al  = alpha_p[0];
    const float bv0 = bi[c0], bv1 = bi[c0 + 1];

#pragma unroll
    for (int mi = 0; mi < 16; ++mi) {
        const int m  = m0 + mi;
        const int mu = (m - 1 < 0) ? 0 : m - 1;
        const int md = (m + 1 > M_ - 1) ? M_ - 1 : m + 1;
        float2 fu = *reinterpret_cast<const float2*>(fin + ((size_t)(b * M_ + mu)) * D_ + c0);
        float2 fd = *reinterpret_cast<const float2*>(fin + ((size_t)(b * M_ + md)) * D_ + c0);
        float f0v = fs[mi][c0], f1v = fs[mi][c0 + 1];
        float lap0 = fu.x + fd.x - 2.f * f0v;
        float lap1 = fu.y + fd.y - 2.f * f1v;
        float it0 = tanhf(acc0[mi] + bv0);
        float it1 = tanhf(acc1[mi] + bv1);
        float2 o;
        o.x = f0v + DT_ * (al * lap0 + it0);
        o.y = f1v + DT_ * (al * lap1 + it1);
        *reinterpret_cast<float2*>(fout + ((size_t)(b * M_ + m)) * D_ + c0) = o;
    }
}

// ---------------------------------------------------------------------------
// Kernel 3: sampled = lerp(field)  ->  enhanced = LN1(sampled + x)  (LDS tile)
//           out = enhanced @ W_out + b_out  ->  LN2(out + enhanced) -> d_out
// grid (N/32, B), 256 threads (4 waves, 8 rows each for the LN phases).
// ---------------------------------------------------------------------------
__global__ __launch_bounds__(256)
void k_tail(const float* __restrict__ x, const float* __restrict__ pos,
            const float* __restrict__ field,
            const float* __restrict__ g1, const float* __restrict__ b1,
            const float* __restrict__ Wo, const float* __restrict__ bo,
            const float* __restrict__ g2, const float* __restrict__ b2,
            float* __restrict__ out)
{
    const int tid  = threadIdx.x;
    const int b    = blockIdx.y;
    const int n0   = blockIdx.x * 32;
    const int wave = tid >> 6;
    const int lane = tid & 63;
    const int c    = lane * 8;

    __shared__ float enh[32][512];      // 64 KB

    // ---- Phase A: gather + lerp + residual + LN1, one wave per row ----
    for (int i = 0; i < 8; ++i) {
        const int r = wave * 8 + i;
        const int n = n0 + r;
        const float* xr = x + ((size_t)(b * N_ + n)) * D_ + c;
        float4 xa = *reinterpret_cast<const float4*>(xr);
        float4 xb = *reinterpret_cast<const float4*>(xr + 4);

        const float p = pos[b * N_ + n];
        float u = p * (float)(M_ - 1);
        int i0 = (int)floorf(u);
        i0 = (i0 < 0) ? 0 : ((i0 > M_ - 2) ? M_ - 2 : i0);
        const float w = u - (float)i0;

        const float* f0p = field + ((size_t)(b * M_ + i0)) * D_ + c;
        float4 f0a = *reinterpret_cast<const float4*>(f0p);
        float4 f0b = *reinterpret_cast<const float4*>(f0p + 4);
        float4 f1a = *reinterpret_cast<const float4*>(f0p + D_);
        float4 f1b = *reinterpret_cast<const float4*>(f0p + D_ + 4);

        float s[8];
        s[0] = (1.f - w) * f0a.x + w * f1a.x + xa.x;
        s[1] = (1.f - w) * f0a.y + w * f1a.y + xa.y;
        s[2] = (1.f - w) * f0a.z + w * f1a.z + xa.z;
        s[3] = (1.f - w) * f0a.w + w * f1a.w + xa.w;
        s[4] = (1.f - w) * f0b.x + w * f1b.x + xb.x;
        s[5] = (1.f - w) * f0b.y + w * f1b.y + xb.y;
        s[6] = (1.f - w) * f0b.z + w * f1b.z + xb.z;
        s[7] = (1.f - w) * f0b.w + w * f1b.w + xb.w;

        float sum = 0.f, ss = 0.f;
#pragma unroll
        for (int j = 0; j < 8; ++j) { sum += s[j]; ss += s[j] * s[j]; }
#pragma unroll
        for (int off = 32; off > 0; off >>= 1) {
            sum += __shfl_xor(sum, off);
            ss  += __shfl_xor(ss, off);
        }
        const float mu  = sum * (1.f / 512.f);
        const float var = ss * (1.f / 512.f) - mu * mu;
        const float rs  = rsqrtf(var + EPS_);

        float4 ga = *reinterpret_cast<const float4*>(g1 + c);
        float4 gb = *reinterpret_cast<const float4*>(g1 + c + 4);
        float4 ba = *reinterpret_cast<const float4*>(b1 + c);
        float4 bb = *reinterpret_cast<const float4*>(b1 + c + 4);

        float4 ea, eb;
        ea.x = (s[0] - mu) * rs * ga.x + ba.x;
        ea.y = (s[1] - mu) * rs * ga.y + ba.y;
        ea.z = (s[2] - mu) * rs * ga.z + ba.z;
        ea.w = (s[3] - mu) * rs * ga.w + ba.w;
        eb.x = (s[4] - mu) * rs * gb.x + bb.x;
        eb.y = (s[5] - mu) * rs * gb.y + bb.y;
        eb.z = (s[6] - mu) * rs * gb.z + bb.z;
        eb.w = (s[7] - mu) * rs * gb.w + bb.w;
        *reinterpret_cast<float4*>(&enh[r][c])     = ea;
        *reinterpret_cast<float4*>(&enh[r][c + 4]) = eb;
    }
    __syncthreads();

    // ---- Phase B: GEMM  acc[m][2] = enh[m][:] @ W_out[:, cols] ----
    const int c0 = 2 * tid;
    float acc0[32], acc1[32];
#pragma unroll
    for (int i = 0; i < 32; ++i) { acc0[i] = 0.f; acc1[i] = 0.f; }

    for (int k = 0; k < 512; k += 4) {
        float2 w0 = *reinterpret_cast<const float2*>(Wo + (size_t)(k + 0) * D_ + c0);
        float2 w1 = *reinterpret_cast<const float2*>(Wo + (size_t)(k + 1) * D_ + c0);
        float2 w2 = *reinterpret_cast<const float2*>(Wo + (size_t)(k + 2) * D_ + c0);
        float2 w3 = *reinterpret_cast<const float2*>(Wo + (size_t)(k + 3) * D_ + c0);
#pragma unroll
        for (int mi = 0; mi < 32; ++mi) {
            float4 e4 = *reinterpret_cast<const float4*>(&enh[mi][k]);
            acc0[mi] = fmaf(e4.x, w0.x, acc0[mi]);
            acc1[mi] = fmaf(e4.x, w0.y, acc1[mi]);
            acc0[mi] = fmaf(e4.y, w1.x, acc0[mi]);
            acc1[mi] = fmaf(e4.y, w1.y, acc1[mi]);
            acc0[mi] = fmaf(e4.z, w2.x, acc0[mi]);
            acc1[mi] = fmaf(e4.z, w2.y, acc1[mi]);
            acc0[mi] = fmaf(e4.w, w3.x, acc0[mi]);
            acc1[mi] = fmaf(e4.w, w3.y, acc1[mi]);
        }
    }
    __syncthreads();

    // ---- Phase C: out_plus = acc + b_out + enhanced (in-place in LDS) ----
    const float bo0 = bo[c0], bo1 = bo[c0 + 1];
#pragma unroll
    for (int mi = 0; mi < 32; ++mi) {
        float2 e = *reinterpret_cast<const float2*>(&enh[mi][c0]);
        float2 o;
        o.x = acc0[mi] + bo0 + e.x;
        o.y = acc1[mi] + bo1 + e.y;
        *reinterpret_cast<float2*>(&enh[mi][c0]) = o;
    }
    __syncthreads();

    // ---- Phase D: LN2 per row, write to global ----
    for (int i = 0; i < 8; ++i) {
        const int r = wave * 8 + i;
        const int n = n0 + r;
        float4 va = *reinterpret_cast<const float4*>(&enh[r][c]);
        float4 vb = *reinterpret_cast<const float4*>(&enh[r][c + 4]);
        float v[8] = {va.x, va.y, va.z, va.w, vb.x, vb.y, vb.z, vb.w};

        float sum = 0.f, ss = 0.f;
#pragma unroll
        for (int j = 0; j < 8; ++j) { sum += v[j]; ss += v[j] * v[j]; }
#pragma unroll
        for (int off = 32; off > 0; off >>= 1) {
            sum += __shfl_xor(sum, off);
            ss  += __shfl_xor(ss, off);
        }
        const float mu  = sum * (1.f / 512.f);
        const float var = ss * (1.f / 512.f) - mu * mu;
        const float rs  = rsqrtf(var + EPS_);

        float4 ga = *reinterpret_cast<const float4*>(g2 + c);
        float4 gb = *reinterpret_cast<const float4*>(g2 + c + 4);
        float4 ba = *reinterpret_cast<const float4*>(b2 + c);
        float4 bb = *reinterpret_cast<const float4*>(b2 + c + 4);

        float4 oa, ob;
        oa.x = (v[0] - mu) * rs * ga.x + ba.x;
        oa.y = (v[1] - mu) * rs * ga.y + ba.y;
        oa.z = (v[2] - mu) * rs * ga.z + ba.z;
        oa.w = (v[3] - mu) * rs * ga.w + ba.w;
        ob.x = (v[4] - mu) * rs * gb.x + bb.x;
        ob.y = (v[5] - mu) * rs * gb.y + bb.y;
        ob.z = (v[6] - mu) * rs * gb.z + bb.z;
        ob.w = (v[7] - mu) * rs * gb.w + bb.w;

        float* orow = out + ((size_t)(b * N_ + n)) * D_ + c;
        *reinterpret_cast<float4*>(orow)     = oa;
        *reinterpret_cast<float4*>(orow + 4) = ob;
    }
}

extern "C" void kernel_launch(void* const* d_in, const int* in_sizes, int n_in,
                              void* d_out, int out_size, void* d_ws, size_t ws_size,
                              hipStream_t stream) {
    (void)in_sizes; (void)n_in; (void)out_size; (void)ws_size;
    const float* x   = (const float*)d_in[0];
    const float* pos = (const float*)d_in[1];
    const float* gp  = (const float*)d_in[2];
    const float* ls  = (const float*)d_in[3];
    const float* al  = (const float*)d_in[4];
    const float* Wi  = (const float*)d_in[5];
    const float* bi  = (const float*)d_in[6];
    const float* g1  = (const float*)d_in[7];
    const float* b1  = (const float*)d_in[8];
    const float* Wo  = (const float*)d_in[9];
    const float* bo  = (const float*)d_in[10];
    const float* g2  = (const float*)d_in[11];
    const float* b2  = (const float*)d_in[12];
    float* out = (float*)d_out;

    float* f0 = (float*)d_ws;                          // [B,M,D] fp32 = 8 MB
    float* f1 = f0 + (size_t)B_ * M_ * D_;             // ping-pong buffer

    k_project<<<dim3(M_ / 16, B_), 256, 0, stream>>>(x, pos, gp, ls, f0);
    k_diffuse<<<dim3(M_ / 16, B_), 256, 0, stream>>>(f0, Wi, bi, al, f1);
    k_diffuse<<<dim3(M_ / 16, B_), 256, 0, stream>>>(f1, Wi, bi, al, f0);
    k_diffuse<<<dim3(M_ / 16, B_), 256, 0, stream>>>(f0, Wi, bi, al, f1);
    k_diffuse<<<dim3(M_ / 16, B_), 256, 0, stream>>>(f1, Wi, bi, al, f0);
    k_tail   <<<dim3(N_ / 32, B_), 256, 0, stream>>>(x, pos, f0, g1, b1, Wo, bo, g2, b2, out);
}

// Round 2
// 282.390 us; speedup vs baseline: 3.9800x; 3.9800x over previous
//
#include <hip/hip_runtime.h>
#include <cmath>

#define B_ 8
#define N_ 4096
#define D_ 512
#define M_ 512
#define EPS_ 1e-5f
#define DT_ 0.25f

typedef unsigned short u16;
typedef unsigned int u32;
typedef __attribute__((ext_vector_type(8))) u16 u16x8;
typedef __attribute__((ext_vector_type(8))) short bf16x8;
typedef __attribute__((ext_vector_type(4))) float f32x4;

__device__ __forceinline__ u16 f2bf(float f) {
    u32 u = __builtin_bit_cast(u32, f);
    u32 r = u + 0x7fffu + ((u >> 16) & 1u);   // round-to-nearest-even
    return (u16)(r >> 16);
}
__device__ __forceinline__ float bf2f(u16 h) {
    return __builtin_bit_cast(float, (u32)h << 16);
}

// ---------------------------------------------------------------------------
// Transpose + fp32->bf16: src [Z][R][C] -> dst [Z][C][R]
// ---------------------------------------------------------------------------
__global__ __launch_bounds__(256)
void k_prep_T(const float* __restrict__ src, u16* __restrict__ dst, int R, int C)
{
    __shared__ float tile[64][65];
    const int t = threadIdx.x;
    const int c0 = blockIdx.x * 64;
    const int r0 = blockIdx.y * 64;
    const int z  = blockIdx.z;
    const float* s = src + (size_t)z * R * C;
    u16* d = dst + (size_t)z * R * C;
    const int rl = t >> 4, cc = (t & 15) * 4;
#pragma unroll
    for (int i = 0; i < 4; ++i) {
        float4 v = *reinterpret_cast<const float4*>(s + (size_t)(r0 + rl + i * 16) * C + c0 + cc);
        tile[rl + i * 16][cc + 0] = v.x;
        tile[rl + i * 16][cc + 1] = v.y;
        tile[rl + i * 16][cc + 2] = v.z;
        tile[rl + i * 16][cc + 3] = v.w;
    }
    __syncthreads();
#pragma unroll
    for (int i = 0; i < 2; ++i) {
        int q = t + i * 256;
        int cl = q >> 3, rc = (q & 7) * 8;
        u16x8 o;
#pragma unroll
        for (int j = 0; j < 8; ++j) o[j] = f2bf(tile[rc + j][cl]);
        *reinterpret_cast<u16x8*>(d + (size_t)(c0 + cl) * R + r0 + rc) = o;
    }
}

// ---------------------------------------------------------------------------
// Projection: field[b] = kern[M,N] @ x[N,D] via bf16 MFMA.
// grid (M/64, D/64, B), 256 thr (2x2 waves). kern computed in-kernel.
// ---------------------------------------------------------------------------
__global__ __launch_bounds__(256)
void k_project(const float* __restrict__ pos, const float* __restrict__ gp,
               const float* __restrict__ log_sigma, const u16* __restrict__ xT,
               float* __restrict__ field)
{
    __shared__ u16 As[64][72];   // kern [m][n], +8 pad -> 2-way-free b128 reads
    __shared__ u16 Bs[64][72];   // xT   [d][n]
    const int t = threadIdx.x;
    const int m0 = blockIdx.x * 64, d0 = blockIdx.y * 64;
    const int b = blockIdx.z;
    const int l = t & 63, wid = t >> 6;
    const int wm = wid >> 1, wn = wid & 1;

    const float sigma = __expf(log_sigma[0]);
    const float ninv2s2 = -0.5f / (sigma * sigma);
    const int am = t & 63;
    const int ac = t >> 6;
    const float gm = gp[(size_t)b * M_ + m0 + am];
    const float* pb = pos + (size_t)b * N_;
    const u16* xb = xT + ((size_t)b * D_ + d0) * N_;

    f32x4 acc[2][2];
#pragma unroll
    for (int i = 0; i < 2; ++i)
#pragma unroll
        for (int j = 0; j < 2; ++j) acc[i][j] = (f32x4){0.f, 0.f, 0.f, 0.f};

    for (int n0 = 0; n0 < N_; n0 += 64) {
        __syncthreads();
        // stage A: kern tile (16 exps/thread)
#pragma unroll
        for (int h = 0; h < 2; ++h) {
            const int ch = (ac + h * 4) * 8;
            float4 p0 = *reinterpret_cast<const float4*>(pb + n0 + ch);
            float4 p1 = *reinterpret_cast<const float4*>(pb + n0 + ch + 4);
            float dv[8] = {gm - p0.x, gm - p0.y, gm - p0.z, gm - p0.w,
                           gm - p1.x, gm - p1.y, gm - p1.z, gm - p1.w};
            u16x8 kv;
#pragma unroll
            for (int j = 0; j < 8; ++j) kv[j] = f2bf(__expf(dv[j] * dv[j] * ninv2s2));
            *reinterpret_cast<u16x8*>(&As[am][ch]) = kv;
        }
        // stage B: xT tile (2x16B/thread)
#pragma unroll
        for (int h = 0; h < 2; ++h) {
            const int q = t + h * 256;
            const int row = q >> 3, cch = (q & 7) * 8;
            u16x8 v = *reinterpret_cast<const u16x8*>(xb + (size_t)row * N_ + n0 + cch);
            *reinterpret_cast<u16x8*>(&Bs[row][cch]) = v;
        }
        __syncthreads();
#pragma unroll
        for (int kk = 0; kk < 64; kk += 32) {
            const int ko = kk + (l >> 4) * 8;
            bf16x8 a0 = *reinterpret_cast<const bf16x8*>(&As[wm * 32 + (l & 15)][ko]);
            bf16x8 a1 = *reinterpret_cast<const bf16x8*>(&As[wm * 32 + 16 + (l & 15)][ko]);
            bf16x8 b0 = *reinterpret_cast<const bf16x8*>(&Bs[wn * 32 + (l & 15)][ko]);
            bf16x8 b1 = *reinterpret_cast<const bf16x8*>(&Bs[wn * 32 + 16 + (l & 15)][ko]);
            acc[0][0] = __builtin_amdgcn_mfma_f32_16x16x32_bf16(a0, b0, acc[0][0], 0, 0, 0);
            acc[0][1] = __builtin_amdgcn_mfma_f32_16x16x32_bf16(a0, b1, acc[0][1], 0, 0, 0);
            acc[1][0] = __builtin_amdgcn_mfma_f32_16x16x32_bf16(a1, b0, acc[1][0], 0, 0, 0);
            acc[1][1] = __builtin_amdgcn_mfma_f32_16x16x32_bf16(a1, b1, acc[1][1], 0, 0, 0);
        }
    }
    const int rb = m0 + wm * 32 + (l >> 4) * 4;
    const int cb = d0 + wn * 32 + (l & 15);
#pragma unroll
    for (int mf = 0; mf < 2; ++mf)
#pragma unroll
        for (int nf = 0; nf < 2; ++nf)
#pragma unroll
            for (int r = 0; r < 4; ++r)
                field[((size_t)b * M_ + rb + mf * 16 + r) * D_ + cb + nf * 16] = acc[mf][nf][r];
}

// ---------------------------------------------------------------------------
// Diffusion step: fout = fin + dt*(alpha*lap + tanh(fin @ Wi + bi))
// grid (M/16, D/256, B), 256 thr (4 waves n-split). W-frags direct from L2.
// ---------------------------------------------------------------------------
__global__ __launch_bounds__(256)
void k_diffuse(const float* __restrict__ fin, const u16* __restrict__ WiT,
               const float* __restrict__ bi, const float* __restrict__ alpha_p,
               float* __restrict__ fout)
{
    __shared__ u16 fs[16][520];
    const int t = threadIdx.x;
    const int m0 = blockIdx.x * 16;
    const int cb0 = blockIdx.y * 256;
    const int b = blockIdx.z;
    const int l = t & 63, wn = t >> 6;
    const float* fb = fin + (size_t)b * M_ * D_;

    {
        const int row = t >> 4, ch = (t & 15) * 32;
        const float* src = fb + (size_t)(m0 + row) * D_ + ch;
#pragma unroll
        for (int j = 0; j < 4; ++j) {
            float4 v0 = *reinterpret_cast<const float4*>(src + j * 8);
            float4 v1 = *reinterpret_cast<const float4*>(src + j * 8 + 4);
            u16x8 o;
            o[0] = f2bf(v0.x); o[1] = f2bf(v0.y); o[2] = f2bf(v0.z); o[3] = f2bf(v0.w);
            o[4] = f2bf(v1.x); o[5] = f2bf(v1.y); o[6] = f2bf(v1.z); o[7] = f2bf(v1.w);
            *reinterpret_cast<u16x8*>(&fs[row][ch + j * 8]) = o;
        }
    }
    __syncthreads();

    f32x4 acc[4];
#pragma unroll
    for (int i = 0; i < 4; ++i) acc[i] = (f32x4){0.f, 0.f, 0.f, 0.f};
    const int colb = cb0 + wn * 64;

    for (int kk = 0; kk < D_; kk += 32) {
        const int ko = kk + (l >> 4) * 8;
        bf16x8 a = *reinterpret_cast<const bf16x8*>(&fs[l & 15][ko]);
#pragma unroll
        for (int nf = 0; nf < 4; ++nf) {
            bf16x8 w = *reinterpret_cast<const bf16x8*>(WiT + (size_t)(colb + nf * 16 + (l & 15)) * D_ + ko);
            acc[nf] = __builtin_amdgcn_mfma_f32_16x16x32_bf16(a, w, acc[nf], 0, 0, 0);
        }
    }

    const float al = alpha_p[0];
    float* fob = fout + (size_t)b * M_ * D_;
#pragma unroll
    for (int nf = 0; nf < 4; ++nf) {
        const int col = colb + nf * 16 + (l & 15);
        const float bic = bi[col];
#pragma unroll
        for (int r = 0; r < 4; ++r) {
            const int m = m0 + (l >> 4) * 4 + r;
            const int mu_ = m > 0 ? m - 1 : 0;
            const int md = m < M_ - 1 ? m + 1 : M_ - 1;
            float fc = fb[(size_t)m * D_ + col];
            float fl_ = fb[(size_t)mu_ * D_ + col];
            float fr_ = fb[(size_t)md * D_ + col];
            float lap = fl_ + fr_ - 2.f * fc;
            fob[(size_t)m * D_ + col] = fc + DT_ * (al * lap + tanhf(acc[nf][r] + bic));
        }
    }
}

// ---------------------------------------------------------------------------
// Tail: lerp+residual+LN1 -> enh(bf16,LDS) -> GEMM vs WoT -> +bo+enh -> LN2
// grid (N/64, B), 512 thr (8 waves, 2x4).
// ---------------------------------------------------------------------------
__global__ __launch_bounds__(512)
void k_tail(const float* __restrict__ x, const float* __restrict__ pos,
            const float* __restrict__ field, const float* __restrict__ g1,
            const float* __restrict__ b1, const u16* __restrict__ WoT,
            const float* __restrict__ bo, const float* __restrict__ g2,
            const float* __restrict__ b2, float* __restrict__ out)
{
    __shared__ u16 As[64][520];      // enh bf16, full K resident (66.6 KB)
    __shared__ float red[64][4][2];  // cross-wave LN2 partials
    const int t = threadIdx.x;
    const int n0 = blockIdx.x * 64;
    const int b = blockIdx.y;
    const int l = t & 63, wid = t >> 6;
    const int wm = wid >> 2, wn = wid & 3;
    const int c = l * 8;

    // ---- Phase A: lerp + residual + LN1 -> As (8 rows per wave) ----
#pragma unroll 1
    for (int i = 0; i < 8; ++i) {
        const int r = wid * 8 + i;
        const int n = n0 + r;
        const float* xr = x + ((size_t)b * N_ + n) * D_ + c;
        float4 xa = *reinterpret_cast<const float4*>(xr);
        float4 xb = *reinterpret_cast<const float4*>(xr + 4);
        const float p = pos[(size_t)b * N_ + n];
        float u = p * (float)(M_ - 1);
        int i0 = (int)floorf(u);
        i0 = i0 < 0 ? 0 : (i0 > M_ - 2 ? M_ - 2 : i0);
        const float w = u - (float)i0;
        const float* fp0 = field + ((size_t)b * M_ + i0) * D_ + c;
        float4 f0a = *reinterpret_cast<const float4*>(fp0);
        float4 f0b = *reinterpret_cast<const float4*>(fp0 + 4);
        float4 f1a = *reinterpret_cast<const float4*>(fp0 + D_);
        float4 f1b = *reinterpret_cast<const float4*>(fp0 + D_ + 4);
        float s[8];
        s[0] = f0a.x + w * (f1a.x - f0a.x) + xa.x;
        s[1] = f0a.y + w * (f1a.y - f0a.y) + xa.y;
        s[2] = f0a.z + w * (f1a.z - f0a.z) + xa.z;
        s[3] = f0a.w + w * (f1a.w - f0a.w) + xa.w;
        s[4] = f0b.x + w * (f1b.x - f0b.x) + xb.x;
        s[5] = f0b.y + w * (f1b.y - f0b.y) + xb.y;
        s[6] = f0b.z + w * (f1b.z - f0b.z) + xb.z;
        s[7] = f0b.w + w * (f1b.w - f0b.w) + xb.w;

        float sum = 0.f, ss = 0.f;
#pragma unroll
        for (int j = 0; j < 8; ++j) { sum += s[j]; ss += s[j] * s[j]; }
#pragma unroll
        for (int off = 1; off <= 32; off <<= 1) {
            sum += __shfl_xor(sum, off);
            ss  += __shfl_xor(ss, off);
        }
        const float mu = sum * (1.f / 512.f);
        const float rs = rsqrtf(ss * (1.f / 512.f) - mu * mu + EPS_);

        float4 ga = *reinterpret_cast<const float4*>(g1 + c);
        float4 gb = *reinterpret_cast<const float4*>(g1 + c + 4);
        float4 ba = *reinterpret_cast<const float4*>(b1 + c);
        float4 bb = *reinterpret_cast<const float4*>(b1 + c + 4);
        u16x8 e;
        e[0] = f2bf((s[0] - mu) * rs * ga.x + ba.x);
        e[1] = f2bf((s[1] - mu) * rs * ga.y + ba.y);
        e[2] = f2bf((s[2] - mu) * rs * ga.z + ba.z);
        e[3] = f2bf((s[3] - mu) * rs * ga.w + ba.w);
        e[4] = f2bf((s[4] - mu) * rs * gb.x + bb.x);
        e[5] = f2bf((s[5] - mu) * rs * gb.y + bb.y);
        e[6] = f2bf((s[6] - mu) * rs * gb.z + bb.z);
        e[7] = f2bf((s[7] - mu) * rs * gb.w + bb.w);
        *reinterpret_cast<u16x8*>(&As[r][c]) = e;
    }
    __syncthreads();

    // ---- Phase B: GEMM, barrier-free K-loop (As static, WoT from L2) ----
    f32x4 acc[2][8];
#pragma unroll
    for (int i = 0; i < 2; ++i)
#pragma unroll
        for (int j = 0; j < 8; ++j) acc[i][j] = (f32x4){0.f, 0.f, 0.f, 0.f};

    for (int kk = 0; kk < D_; kk += 32) {
        const int ko = kk + (l >> 4) * 8;
        bf16x8 a0 = *reinterpret_cast<const bf16x8*>(&As[wm * 32 + (l & 15)][ko]);
        bf16x8 a1 = *reinterpret_cast<const bf16x8*>(&As[wm * 32 + 16 + (l & 15)][ko]);
#pragma unroll
        for (int nf = 0; nf < 8; ++nf) {
            const int col = wn * 128 + nf * 16 + (l & 15);
            bf16x8 bw = *reinterpret_cast<const bf16x8*>(WoT + (size_t)col * D_ + ko);
            acc[0][nf] = __builtin_amdgcn_mfma_f32_16x16x32_bf16(a0, bw, acc[0][nf], 0, 0, 0);
            acc[1][nf] = __builtin_amdgcn_mfma_f32_16x16x32_bf16(a1, bw, acc[1][nf], 0, 0, 0);
        }
    }

    // ---- Phase C: + bias + enh residual, partial LN2 sums ----
    float psum[2][4], pss[2][4];
#pragma unroll
    for (int mf = 0; mf < 2; ++mf)
#pragma unroll
        for (int r = 0; r < 4; ++r) { psum[mf][r] = 0.f; pss[mf][r] = 0.f; }

#pragma unroll
    for (int nf = 0; nf < 8; ++nf) {
        const int col = wn * 128 + nf * 16 + (l & 15);
        const float boc = bo[col];
#pragma unroll
        for (int mf = 0; mf < 2; ++mf)
#pragma unroll
            for (int r = 0; r < 4; ++r) {
                const int row = wm * 32 + mf * 16 + (l >> 4) * 4 + r;
                float v = acc[mf][nf][r] + boc + bf2f(As[row][col]);
                acc[mf][nf][r] = v;
                psum[mf][r] += v;
                pss[mf][r]  += v * v;
            }
    }
#pragma unroll
    for (int off = 1; off <= 8; off <<= 1) {
#pragma unroll
        for (int mf = 0; mf < 2; ++mf)
#pragma unroll
            for (int r = 0; r < 4; ++r) {
                psum[mf][r] += __shfl_xor(psum[mf][r], off);
                pss[mf][r]  += __shfl_xor(pss[mf][r], off);
            }
    }
    if ((l & 15) == 0) {
#pragma unroll
        for (int mf = 0; mf < 2; ++mf)
#pragma unroll
            for (int r = 0; r < 4; ++r) {
                const int row = wm * 32 + mf * 16 + (l >> 4) * 4 + r;
                red[row][wn][0] = psum[mf][r];
                red[row][wn][1] = pss[mf][r];
            }
    }
    __syncthreads();

    // ---- Phase D: LN2 + store ----
#pragma unroll
    for (int mf = 0; mf < 2; ++mf)
#pragma unroll
        for (int r = 0; r < 4; ++r) {
            const int row = wm * 32 + mf * 16 + (l >> 4) * 4 + r;
            float s  = red[row][0][0] + red[row][1][0] + red[row][2][0] + red[row][3][0];
            float ss = red[row][0][1] + red[row][1][1] + red[row][2][1] + red[row][3][1];
            float mu = s * (1.f / 512.f);
            float rs = rsqrtf(ss * (1.f / 512.f) - mu * mu + EPS_);
#pragma unroll
            for (int nf = 0; nf < 8; ++nf) {
                const int col = wn * 128 + nf * 16 + (l & 15);
                out[((size_t)b * N_ + n0 + row) * D_ + col] =
                    (acc[mf][nf][r] - mu) * rs * g2[col] + b2[col];
            }
        }
}

extern "C" void kernel_launch(void* const* d_in, const int* in_sizes, int n_in,
                              void* d_out, int out_size, void* d_ws, size_t ws_size,
                              hipStream_t stream) {
    (void)in_sizes; (void)n_in; (void)out_size; (void)ws_size;
    const float* x   = (const float*)d_in[0];
    const float* pos = (const float*)d_in[1];
    const float* gp  = (const float*)d_in[2];
    const float* ls  = (const float*)d_in[3];
    const float* al  = (const float*)d_in[4];
    const float* Wi  = (const float*)d_in[5];
    const float* bi  = (const float*)d_in[6];
    const float* g1  = (const float*)d_in[7];
    const float* b1  = (const float*)d_in[8];
    const float* Wo  = (const float*)d_in[9];
    const float* bo  = (const float*)d_in[10];
    const float* g2  = (const float*)d_in[11];
    const float* b2  = (const float*)d_in[12];
    float* out = (float*)d_out;

    float* f0 = (float*)d_ws;                              // 8 MB fp32 field
    float* f1 = f0 + (size_t)B_ * M_ * D_;                 // 8 MB ping-pong
    u16* xT  = (u16*)(f1 + (size_t)B_ * M_ * D_);          // 32 MB bf16 x^T
    u16* WiT = xT + (size_t)B_ * D_ * N_;                  // 512 KB
    u16* WoT = WiT + (size_t)D_ * D_;                      // 512 KB

    k_prep_T<<<dim3(D_ / 64, N_ / 64, B_), 256, 0, stream>>>(x, xT, N_, D_);
    k_prep_T<<<dim3(D_ / 64, D_ / 64, 1), 256, 0, stream>>>(Wi, WiT, D_, D_);
    k_prep_T<<<dim3(D_ / 64, D_ / 64, 1), 256, 0, stream>>>(Wo, WoT, D_, D_);
    k_project<<<dim3(M_ / 64, D_ / 64, B_), 256, 0, stream>>>(pos, gp, ls, xT, f0);
    k_diffuse<<<dim3(M_ / 16, D_ / 256, B_), 256, 0, stream>>>(f0, WiT, bi, al, f1);
    k_diffuse<<<dim3(M_ / 16, D_ / 256, B_), 256, 0, stream>>>(f1, WiT, bi, al, f0);
    k_diffuse<<<dim3(M_ / 16, D_ / 256, B_), 256, 0, stream>>>(f0, WiT, bi, al, f1);
    k_diffuse<<<dim3(M_ / 16, D_ / 256, B_), 256, 0, stream>>>(f1, WiT, bi, al, f0);
    k_tail<<<dim3(N_ / 64, B_), 512, 0, stream>>>(x, pos, f0, g1, b1, WoT, bo, g2, b2, out);
}